// Round 9
// baseline (213.084 us; speedup 1.0000x reference)
//
#include <hip/hip_runtime.h>
#include <hip/hip_bf16.h>
#include <hip/hip_cooperative_groups.h>

namespace cg = cooperative_groups;

#define T_ROWS 16384
#define J_DIM  1024
#define D_DIM  512

typedef __attribute__((ext_vector_type(8))) short bf16x8;
typedef __attribute__((ext_vector_type(4))) float f32x4;
typedef unsigned short u16;

__device__ __forceinline__ u16 f2bf(float f) {
    union { float f; unsigned int u; } v; v.f = f;
    return (u16)((v.u + 0x7FFFu + ((v.u >> 16) & 1u)) >> 16);  // RNE
}
__device__ __forceinline__ float bf2f(u16 b) {
    union { unsigned int u; float f; } v; v.u = ((unsigned int)b) << 16;
    return v.f;
}

// async global->LDS, 16B per lane. LDS dest must be wave-uniform base + lane*16.
__device__ __forceinline__ void gload16(const void* g, void* l) {
    __builtin_amdgcn_global_load_lds(
        (__attribute__((address_space(1))) void*)(unsigned long long)(size_t)g,
        (__attribute__((address_space(3))) void*)(unsigned int)(size_t)l,
        16, 0, 0);
}

// ---------------------------------------------------------------------------
// m97-style 128x128 tile GEMM core, BK=32, bf16 MFMA 16x16x32 (kept).
// ---------------------------------------------------------------------------
template<int NT>
__device__ __forceinline__ void gemm_core(
    const u16* A, int lda, const u16* B, int ldb, u16* lds, f32x4 (&acc)[4][4])
{
    const int tid  = threadIdx.x;
    const int lane = tid & 63;
    const int w    = tid >> 6;
    const int wr   = w >> 1, wc = w & 1;
    const int fr   = lane & 15, quad = lane >> 4;

    const int srow = tid >> 2;
    const int ss   = (tid & 3) ^ ((srow >> 1) & 3);

    const u16* gA0 = A + (size_t)srow * lda + ss * 8;
    const u16* gA1 = A + (size_t)(srow + 64) * lda + ss * 8;
    const u16* gB0 = B + (size_t)srow * ldb + ss * 8;
    const u16* gB1 = B + (size_t)(srow + 64) * ldb + ss * 8;

    u16* As = lds;            // [2][4096]
    u16* Bs = lds + 8192;     // [2][4096]
    u16* dA0 = As + tid * 8;
    u16* dA1 = As + 2048 + tid * 8;
    u16* dB0 = Bs + tid * 8;
    u16* dB1 = Bs + 2048 + tid * 8;

    gload16(gA0, dA0); gload16(gA1, dA1);
    gload16(gB0, dB0); gload16(gB1, dB1);
    gA0 += 32; gA1 += 32; gB0 += 32; gB1 += 32;

    int offA[4], offB[4];
    #pragma unroll
    for (int i = 0; i < 4; ++i) {
        const int rA = wr * 64 + i * 16 + fr;
        offA[i] = rA * 32 + (quad ^ ((rA >> 1) & 3)) * 8;
        const int rB = wc * 64 + i * 16 + fr;
        offB[i] = rB * 32 + (quad ^ ((rB >> 1) & 3)) * 8;
    }
    __syncthreads();

    #pragma unroll 2
    for (int t = 0; t < NT; ++t) {
        const int cur = (t & 1) * 4096;
        const int nxt = 4096 - cur;
        if (t + 1 < NT) {
            gload16(gA0, dA0 + nxt); gload16(gA1, dA1 + nxt);
            gload16(gB0, dB0 + nxt); gload16(gB1, dB1 + nxt);
            gA0 += 32; gA1 += 32; gB0 += 32; gB1 += 32;
        }
        const u16* Ac = As + cur;
        const u16* Bc = Bs + cur;
        bf16x8 af[4], bfr[4];
        #pragma unroll
        for (int i = 0; i < 4; ++i) af[i]  = *(const bf16x8*)(Ac + offA[i]);
        #pragma unroll
        for (int i = 0; i < 4; ++i) bfr[i] = *(const bf16x8*)(Bc + offB[i]);
        #pragma unroll
        for (int mf = 0; mf < 4; ++mf)
            #pragma unroll
            for (int nf = 0; nf < 4; ++nf)
                acc[mf][nf] = __builtin_amdgcn_mfma_f32_16x16x32_bf16(
                    af[mf], bfr[nf], acc[mf][nf], 0, 0, 0);
        __syncthreads();
    }
}

// ---------------------------------------------------------------------------
// prep: merged. Blocks [0,4096): H rows -> hw1, Hq=bf16(H*w3) into out u16
// cols [3072:3584). Blocks [4096,4352): U rows -> uw2, Ub row-major, Utp
// fragment-major. Wave per row (4 waves / 256-thread block).
// ---------------------------------------------------------------------------
__global__ __launch_bounds__(256) void prep_kernel(
    const float* __restrict__ H, const float* __restrict__ U,
    const float* __restrict__ Ws,
    float* __restrict__ hw1, float* __restrict__ uw2,
    u16* outU, u16* __restrict__ Ub, u16* __restrict__ Utp)
{
    const int w = threadIdx.x >> 6, lane = threadIdx.x & 63;
    if (blockIdx.x < 4096) {
        const int i = blockIdx.x * 4 + w;
        const float* hp = H + (size_t)i * D_DIM + lane * 8;
        const float4 a = *(const float4*)hp;
        const float4 b = *(const float4*)(hp + 4);
        const float4 w1a = *(const float4*)(Ws + lane * 8);
        const float4 w1b = *(const float4*)(Ws + lane * 8 + 4);
        const float4 w3a = *(const float4*)(Ws + 2 * D_DIM + lane * 8);
        const float4 w3b = *(const float4*)(Ws + 2 * D_DIM + lane * 8 + 4);
        float p = a.x*w1a.x + a.y*w1a.y + a.z*w1a.z + a.w*w1a.w
                + b.x*w1b.x + b.y*w1b.y + b.z*w1b.z + b.w*w1b.w;
        #pragma unroll
        for (int m = 1; m < 64; m <<= 1) p += __shfl_xor(p, m);
        if (lane == 0) hw1[i] = p;
        bf16x8 q;
        q[0] = (short)f2bf(a.x * w3a.x); q[1] = (short)f2bf(a.y * w3a.y);
        q[2] = (short)f2bf(a.z * w3a.z); q[3] = (short)f2bf(a.w * w3a.w);
        q[4] = (short)f2bf(b.x * w3b.x); q[5] = (short)f2bf(b.y * w3b.y);
        q[6] = (short)f2bf(b.z * w3b.z); q[7] = (short)f2bf(b.w * w3b.w);
        *(bf16x8*)(outU + (size_t)i * 4096 + 3072 + lane * 8) = q;
    } else {
        const int j = (blockIdx.x - 4096) * 4 + w;
        const float* up = U + (size_t)j * D_DIM + lane * 8;
        const float4 a = *(const float4*)up;
        const float4 b = *(const float4*)(up + 4);
        const float4 w2a = *(const float4*)(Ws + D_DIM + lane * 8);
        const float4 w2b = *(const float4*)(Ws + D_DIM + lane * 8 + 4);
        float p = a.x*w2a.x + a.y*w2a.y + a.z*w2a.z + a.w*w2a.w
                + b.x*w2b.x + b.y*w2b.y + b.z*w2b.z + b.w*w2b.w;
        #pragma unroll
        for (int m = 1; m < 64; m <<= 1) p += __shfl_xor(p, m);
        if (lane == 0) uw2[j] = p;
        bf16x8 q;
        q[0] = (short)f2bf(a.x); q[1] = (short)f2bf(a.y);
        q[2] = (short)f2bf(a.z); q[3] = (short)f2bf(a.w);
        q[4] = (short)f2bf(b.x); q[5] = (short)f2bf(b.y);
        q[6] = (short)f2bf(b.z); q[7] = (short)f2bf(b.w);
        *(bf16x8*)(Ub + (size_t)j * D_DIM + lane * 8) = q;
        const size_t jpart = (size_t)(j >> 5) * 512
                           + (size_t)(((j >> 3) & 3) * 128) + (j & 7);
        #pragma unroll
        for (int s = 0; s < 8; ++s) {
            const int d = lane * 8 + s;
            Utp[(size_t)(d >> 4) * 16384 + jpart + (size_t)(d & 15) * 8] = (u16)q[s];
        }
    }
}

// ---------------------------------------------------------------------------
// s_gemm: S = Hq @ Ub^T + uw2 -> bf16 into out u16 cols [1024:2048) via LDS
// transpose (coalesced 128B/thread stores); pmax[row*8+nb] = local row max.
// ---------------------------------------------------------------------------
__global__ __launch_bounds__(256) void s_gemm(
    u16* outU, const u16* __restrict__ Ub, const float* __restrict__ uw2,
    float* __restrict__ pmax)
{
    __shared__ u16 lds[16896];      // staging [0:16384); Tl [128][132] after
    __shared__ float redf[256];
    const int bid = blockIdx.x;                       // 1024
    const int swz = (bid & 7) * 128 + (bid >> 3);     // XCD swizzle (bijective)
    const int bm = swz >> 3, nb = swz & 7;            // nb fast: A-panel reuse

    f32x4 acc[4][4];
    #pragma unroll
    for (int i = 0; i < 4; ++i)
        #pragma unroll
        for (int j = 0; j < 4; ++j) acc[i][j] = (f32x4){0.f, 0.f, 0.f, 0.f};

    gemm_core<16>(outU + (size_t)bm * 128 * 4096 + 3072, 4096,
                  Ub + (size_t)nb * 128 * 512, 512, lds, acc);

    const int tid = threadIdx.x, lane = tid & 63, w = tid >> 6;
    const int wr = w >> 1, wc = w & 1, fr = lane & 15, quad = lane >> 4;
    float u2[4];
    #pragma unroll
    for (int nf = 0; nf < 4; ++nf) u2[nf] = uw2[nb * 128 + wc * 64 + nf * 16 + fr];

    // add uw2; per-row max -> redf; bf16 into padded transpose tile Tl
    u16* Tl = lds;                                    // [128][132]
    #pragma unroll
    for (int mf = 0; mf < 4; ++mf)
        #pragma unroll
        for (int m = 0; m < 4; ++m) {
            const int row = wr * 64 + mf * 16 + quad * 4 + m;
            float mv = -1e30f;
            #pragma unroll
            for (int nf = 0; nf < 4; ++nf) {
                acc[mf][nf][m] += u2[nf];
                mv = fmaxf(mv, acc[mf][nf][m]);
            }
            mv = fmaxf(mv, __shfl_xor(mv, 1));
            mv = fmaxf(mv, __shfl_xor(mv, 2));
            mv = fmaxf(mv, __shfl_xor(mv, 4));
            mv = fmaxf(mv, __shfl_xor(mv, 8));
            if (fr == 0) redf[wc * 128 + row] = mv;
            #pragma unroll
            for (int nf = 0; nf < 4; ++nf)
                Tl[row * 132 + wc * 64 + nf * 16 + fr] = f2bf(acc[mf][nf][m]);
        }
    __syncthreads();

    if (wc == 0 && fr == 0) {
        #pragma unroll
        for (int mf = 0; mf < 4; ++mf)
            #pragma unroll
            for (int m = 0; m < 4; ++m) {
                const int rr = wr * 64 + mf * 16 + quad * 4 + m;
                pmax[((size_t)bm * 128 + rr) * 8 + nb] =
                    fmaxf(redf[rr], redf[128 + rr]);
            }
    }

    // coalesced copy: 2 threads per row -> 128B contiguous each (u16 units!)
    {
        const int rr = tid >> 1, hf = tid & 1;
        const u16* src = Tl + rr * 132 + hf * 64;
        u16* dst = outU + (size_t)(bm * 128 + rr) * 4096 + 1024 + nb * 128 + hf * 64;
        #pragma unroll
        for (int i = 0; i < 8; ++i)
            *(bf16x8*)(dst + i * 8) = *(const bf16x8*)(src + i * 8);
    }
}

// ---------------------------------------------------------------------------
// stats_coop: cooperative kernel replacing bsoft2 + htilde_partial +
// htilde_reduce. 256 blocks x 512 threads, 64 rows per block.
//   P1: rs_i = max_nb(pmax) + hw1_i (coalesced: pmax[b*512+t]); block max.
//   P2: global M; esh = exp(rs - M); partial L.
//   P3: global L; part[b][d] = invL * sum_i esh_i * H[i][d].
//   P4: block 0 reduces part -> htld.
// ---------------------------------------------------------------------------
__global__ __launch_bounds__(512) void stats_coop(
    const float* __restrict__ pmax, const float* __restrict__ hw1,
    const float* __restrict__ H,
    float* __restrict__ partM, float* __restrict__ partL,
    float* __restrict__ part, float* __restrict__ htld)
{
    cg::grid_group grid = cg::this_grid();
    const int b = blockIdx.x;     // 256
    const int t = threadIdx.x;    // 512
    __shared__ float rssh[64];
    __shared__ float esh[64];
    __shared__ float red8[8];
    __shared__ float Msh, Lsh;

    // Phase 1
    {
        const int r = b * 64 + (t >> 3);
        float v = pmax[(size_t)b * 512 + t];          // == pmax[r*8 + (t&7)]
        v = fmaxf(v, __shfl_xor(v, 1));
        v = fmaxf(v, __shfl_xor(v, 2));
        v = fmaxf(v, __shfl_xor(v, 4));
        const float rs = v + hw1[r];
        if ((t & 7) == 0) rssh[t >> 3] = rs;
        float bm = rs;
        bm = fmaxf(bm, __shfl_xor(bm, 8));
        bm = fmaxf(bm, __shfl_xor(bm, 16));
        bm = fmaxf(bm, __shfl_xor(bm, 32));
        if ((t & 63) == 0) red8[t >> 6] = bm;
        __syncthreads();
        if (t == 0) {
            float M = red8[0];
            #pragma unroll
            for (int i = 1; i < 8; ++i) M = fmaxf(M, red8[i]);
            partM[b] = M;
        }
    }
    grid.sync();
    // Phase 2
    {
        float m = (t < 256) ? partM[t] : -1e30f;
        #pragma unroll
        for (int s = 1; s < 64; s <<= 1) m = fmaxf(m, __shfl_xor(m, s));
        if ((t & 63) == 0) red8[t >> 6] = m;
        __syncthreads();
        if (t == 0) {
            float M = red8[0];
            #pragma unroll
            for (int i = 1; i < 8; ++i) M = fmaxf(M, red8[i]);
            Msh = M;
        }
        __syncthreads();
        const float M = Msh;
        if (t < 64) esh[t] = __expf(rssh[t] - M);
        __syncthreads();
        if (t == 0) {
            float l = 0.f;
            #pragma unroll 8
            for (int i = 0; i < 64; ++i) l += esh[i];
            partL[b] = l;
        }
    }
    grid.sync();
    // Phase 3
    {
        float l = (t < 256) ? partL[t] : 0.f;
        #pragma unroll
        for (int s = 1; s < 64; s <<= 1) l += __shfl_xor(l, s);
        if ((t & 63) == 0) red8[t >> 6] = l;
        __syncthreads();
        if (t == 0) {
            float L = 0.f;
            #pragma unroll
            for (int i = 0; i < 8; ++i) L += red8[i];
            Lsh = L;
        }
        __syncthreads();
        const float invL = 1.f / Lsh;
        float s = 0.f;
        const float* hp = H + (size_t)b * 64 * D_DIM + t;
        #pragma unroll 8
        for (int ri = 0; ri < 64; ++ri)
            s += esh[ri] * hp[(size_t)ri * D_DIM];
        part[(size_t)b * D_DIM + t] = s * invL;
    }
    grid.sync();
    // Phase 4
    if (b == 0) {
        float s = 0.f;
        for (int p = 0; p < 256; ++p) s += part[(size_t)p * D_DIM + t];
        htld[t] = s;
    }
}

// ---------------------------------------------------------------------------
// pv_fused: block = 32 rows x all 512 d, 512 threads, 2 blocks/CU. (R8, kept)
// ---------------------------------------------------------------------------
__global__ __launch_bounds__(512, 4) void pv_fused(
    u16* outU, const u16* __restrict__ Utp, const float* __restrict__ H,
    const float* __restrict__ htld)
{
    __shared__ float SPf[32 * 520];          // 66560 B; aliased as u16 P buffer
    u16* SP = (u16*)SPf;                     // [32][1024] u16 (64 KB region)
    const int tid = threadIdx.x, lane = tid & 63, w = tid >> 6;
    const int fr = lane & 15, quad = lane >> 4;
    const int ib = blockIdx.x * 32;

    // Phase 1: stage S rows [ib, ib+32): 8 passes x 512 lanes x 16B
    #pragma unroll
    for (int p = 0; p < 8; ++p) {
        const int slot = p * 512 + tid;      // 0..4095
        const int r  = slot >> 7;            // 0..31
        const int c8 = slot & 127;
        gload16(outU + (size_t)(ib + r) * 4096 + 1024 + (size_t)((c8 ^ (r & 7)) * 8),
                SP + (size_t)slot * 8);
    }
    __syncthreads();

    // Phase 2: in-place softmax; wave w owns rows [4w, 4w+4)
    #pragma unroll
    for (int rr = 0; rr < 4; ++rr) {
        const int r = w * 4 + rr;
        u16* row = SP + (size_t)r * 1024;
        const int s0 = (lane ^ (r & 7)) * 8;
        const int s1 = ((lane + 64) ^ (r & 7)) * 8;
        bf16x8 x0 = *(bf16x8*)(row + s0);
        bf16x8 x1 = *(bf16x8*)(row + s1);
        float f0[8], f1[8];
        float mx = -1e30f;
        #pragma unroll
        for (int i = 0; i < 8; ++i) {
            f0[i] = bf2f((u16)x0[i]); f1[i] = bf2f((u16)x1[i]);
            mx = fmaxf(mx, fmaxf(f0[i], f1[i]));
        }
        #pragma unroll
        for (int s = 1; s < 64; s <<= 1) mx = fmaxf(mx, __shfl_xor(mx, s));
        float sum = 0.f;
        #pragma unroll
        for (int i = 0; i < 8; ++i) {
            f0[i] = __expf(f0[i] - mx); f1[i] = __expf(f1[i] - mx);
            sum += f0[i] + f1[i];
        }
        #pragma unroll
        for (int s = 1; s < 64; s <<= 1) sum += __shfl_xor(sum, s);
        const float inv = 1.f / sum;
        bf16x8 y0, y1;
        #pragma unroll
        for (int i = 0; i < 8; ++i) {
            y0[i] = (short)f2bf(f0[i] * inv);
            y1[i] = (short)f2bf(f1[i] * inv);
        }
        *(bf16x8*)(row + s0) = y0;
        *(bf16x8*)(row + s1) = y1;
    }
    __syncthreads();

    // Phase 3: AQ = P @ Utp; wave w owns d in [64w, 64w+64)
    f32x4 acc[2][4];
    #pragma unroll
    for (int i = 0; i < 2; ++i)
        #pragma unroll
        for (int j = 0; j < 4; ++j) acc[i][j] = (f32x4){0.f, 0.f, 0.f, 0.f};

    const u16* bp = Utp + (size_t)lane * 8;
    bf16x8 bA[4], bB[4];
    #pragma unroll
    for (int nf = 0; nf < 4; ++nf)
        bA[nf] = *(const bf16x8*)(bp + ((size_t)(w * 4 + nf) * 32) * 512);

    for (int ks = 0; ks < 32; ks += 2) {
        #pragma unroll
        for (int nf = 0; nf < 4; ++nf)
            bB[nf] = *(const bf16x8*)(bp + ((size_t)(w * 4 + nf) * 32 + ks + 1) * 512);
        bf16x8 a0[2];
        #pragma unroll
        for (int mf = 0; mf < 2; ++mf)
            a0[mf] = *(const bf16x8*)(SP + (size_t)(mf * 16 + fr) * 1024
                                         + (size_t)(((ks * 4 + quad) ^ (fr & 7)) * 8));
        __builtin_amdgcn_s_setprio(1);
        #pragma unroll
        for (int mf = 0; mf < 2; ++mf)
            #pragma unroll
            for (int nf = 0; nf < 4; ++nf)
                acc[mf][nf] = __builtin_amdgcn_mfma_f32_16x16x32_bf16(
                    a0[mf], bA[nf], acc[mf][nf], 0, 0, 0);
        __builtin_amdgcn_s_setprio(0);
        if (ks + 2 < 32) {
            #pragma unroll
            for (int nf = 0; nf < 4; ++nf)
                bA[nf] = *(const bf16x8*)(bp + ((size_t)(w * 4 + nf) * 32 + ks + 2) * 512);
        }
        bf16x8 a1[2];
        #pragma unroll
        for (int mf = 0; mf < 2; ++mf)
            a1[mf] = *(const bf16x8*)(SP + (size_t)(mf * 16 + fr) * 1024
                                         + (size_t)((((ks + 1) * 4 + quad) ^ (fr & 7)) * 8));
        __builtin_amdgcn_s_setprio(1);
        #pragma unroll
        for (int mf = 0; mf < 2; ++mf)
            #pragma unroll
            for (int nf = 0; nf < 4; ++nf)
                acc[mf][nf] = __builtin_amdgcn_mfma_f32_16x16x32_bf16(
                    a1[mf], bB[nf], acc[mf][nf], 0, 0, 0);
        __builtin_amdgcn_s_setprio(0);
    }
    __syncthreads();   // all P reads done; reuse LDS as f32 AQ buffer

    // Phase 4a: acc -> SPf [row][d] stride 520
    #pragma unroll
    for (int mf = 0; mf < 2; ++mf)
        #pragma unroll
        for (int m = 0; m < 4; ++m) {
            const int r = mf * 16 + quad * 4 + m;
            #pragma unroll
            for (int nf = 0; nf < 4; ++nf)
                SPf[r * 520 + w * 64 + nf * 16 + fr] = acc[mf][nf][m];
        }
    __syncthreads();

    // Phase 4b: coalesced G stores; thread t -> row tid>>4, 8 x float4
    {
        const int r = tid >> 4;              // 0..31
        const int l16 = tid & 15;
        const size_t grow = (size_t)ib + r;
        const float* hrow = H + grow * D_DIM;
        float* ob = (float*)outU + grow * 2048;
        #pragma unroll
        for (int i = 0; i < 8; ++i) {
            const int c = l16 * 4 + i * 64;
            const float4 h  = *(const float4*)(hrow + c);
            const float4 aq = *(const float4*)(&SPf[r * 520 + c]);
            const float4 hv = *(const float4*)(htld + c);
            float4 ha, hh;
            ha.x = h.x * aq.x; ha.y = h.y * aq.y; ha.z = h.z * aq.z; ha.w = h.w * aq.w;
            hh.x = h.x * hv.x; hh.y = h.y * hv.y; hh.z = h.z * hv.z; hh.w = h.w * hv.w;
            *(float4*)(ob + c)        = h;
            *(float4*)(ob + 512 + c)  = aq;
            *(float4*)(ob + 1024 + c) = ha;
            *(float4*)(ob + 1536 + c) = hh;
        }
    }
}

// ---------------------------------------------------------------------------
extern "C" void kernel_launch(void* const* d_in, const int* in_sizes, int n_in,
                              void* d_out, int out_size, void* d_ws, size_t ws_size,
                              hipStream_t stream)
{
    const float* H  = (const float*)d_in[0];
    const float* U  = (const float*)d_in[1];
    const float* Ws = (const float*)d_in[2];
    u16* outU = (u16*)d_out;

    float* uw2   = (float*)d_ws;                   // 1024
    float* hw1   = uw2 + 1024;                     // 16384
    float* htld  = hw1 + T_ROWS;                   // 512
    float* partM = htld + D_DIM;                   // 256
    float* partL = partM + 256;                    // 256
    float* part  = partL + 256;                    // 256*512
    float* pmax  = part + 256 * D_DIM;             // 16384*8
    u16*   Ub    = (u16*)(pmax + (size_t)T_ROWS * 8);   // 1 MB
    u16*   Utp   = Ub + (size_t)J_DIM * D_DIM;          // 1 MB

    hipLaunchKernelGGL(prep_kernel, dim3(4096 + 256), dim3(256), 0, stream,
                       H, U, Ws, hw1, uw2, outU, Ub, Utp);
    hipLaunchKernelGGL(s_gemm, dim3(1024), dim3(256), 0, stream,
                       outU, Ub, uw2, pmax);
    {
        const float* pmax_c = pmax;
        const float* hw1_c  = hw1;
        const float* H_c    = H;
        void* cargs[] = { (void*)&pmax_c, (void*)&hw1_c, (void*)&H_c,
                          (void*)&partM, (void*)&partL, (void*)&part, (void*)&htld };
        hipLaunchCooperativeKernel((const void*)stats_coop, dim3(256), dim3(512),
                                   cargs, 0, stream);
    }
    hipLaunchKernelGGL(pv_fused, dim3(T_ROWS / 32), dim3(512), 0, stream,
                       outU, Utp, H, htld);
}

// Round 10
// 133.364 us; speedup vs baseline: 1.5978x; 1.5978x over previous
//
#include <hip/hip_runtime.h>
#include <hip/hip_bf16.h>

#define T_ROWS 16384
#define J_DIM  1024
#define D_DIM  512

typedef __attribute__((ext_vector_type(8))) short bf16x8;
typedef __attribute__((ext_vector_type(4))) float f32x4;
typedef unsigned short u16;

__device__ __forceinline__ u16 f2bf(float f) {
    union { float f; unsigned int u; } v; v.f = f;
    return (u16)((v.u + 0x7FFFu + ((v.u >> 16) & 1u)) >> 16);  // RNE
}
__device__ __forceinline__ float bf2f(u16 b) {
    union { unsigned int u; float f; } v; v.u = ((unsigned int)b) << 16;
    return v.f;
}

// async global->LDS, 16B per lane. LDS dest must be wave-uniform base + lane*16.
__device__ __forceinline__ void gload16(const void* g, void* l) {
    __builtin_amdgcn_global_load_lds(
        (__attribute__((address_space(1))) void*)(unsigned long long)(size_t)g,
        (__attribute__((address_space(3))) void*)(unsigned int)(size_t)l,
        16, 0, 0);
}

// ---------------------------------------------------------------------------
// m97-style 128x128 tile GEMM core, BK=32, bf16 MFMA 16x16x32 (kept).
// ---------------------------------------------------------------------------
template<int NT>
__device__ __forceinline__ void gemm_core(
    const u16* A, int lda, const u16* B, int ldb, u16* lds, f32x4 (&acc)[4][4])
{
    const int tid  = threadIdx.x;
    const int lane = tid & 63;
    const int w    = tid >> 6;
    const int wr   = w >> 1, wc = w & 1;
    const int fr   = lane & 15, quad = lane >> 4;

    const int srow = tid >> 2;
    const int ss   = (tid & 3) ^ ((srow >> 1) & 3);

    const u16* gA0 = A + (size_t)srow * lda + ss * 8;
    const u16* gA1 = A + (size_t)(srow + 64) * lda + ss * 8;
    const u16* gB0 = B + (size_t)srow * ldb + ss * 8;
    const u16* gB1 = B + (size_t)(srow + 64) * ldb + ss * 8;

    u16* As = lds;            // [2][4096]
    u16* Bs = lds + 8192;     // [2][4096]
    u16* dA0 = As + tid * 8;
    u16* dA1 = As + 2048 + tid * 8;
    u16* dB0 = Bs + tid * 8;
    u16* dB1 = Bs + 2048 + tid * 8;

    gload16(gA0, dA0); gload16(gA1, dA1);
    gload16(gB0, dB0); gload16(gB1, dB1);
    gA0 += 32; gA1 += 32; gB0 += 32; gB1 += 32;

    int offA[4], offB[4];
    #pragma unroll
    for (int i = 0; i < 4; ++i) {
        const int rA = wr * 64 + i * 16 + fr;
        offA[i] = rA * 32 + (quad ^ ((rA >> 1) & 3)) * 8;
        const int rB = wc * 64 + i * 16 + fr;
        offB[i] = rB * 32 + (quad ^ ((rB >> 1) & 3)) * 8;
    }
    __syncthreads();

    #pragma unroll 2
    for (int t = 0; t < NT; ++t) {
        const int cur = (t & 1) * 4096;
        const int nxt = 4096 - cur;
        if (t + 1 < NT) {
            gload16(gA0, dA0 + nxt); gload16(gA1, dA1 + nxt);
            gload16(gB0, dB0 + nxt); gload16(gB1, dB1 + nxt);
            gA0 += 32; gA1 += 32; gB0 += 32; gB1 += 32;
        }
        const u16* Ac = As + cur;
        const u16* Bc = Bs + cur;
        bf16x8 af[4], bfr[4];
        #pragma unroll
        for (int i = 0; i < 4; ++i) af[i]  = *(const bf16x8*)(Ac + offA[i]);
        #pragma unroll
        for (int i = 0; i < 4; ++i) bfr[i] = *(const bf16x8*)(Bc + offB[i]);
        #pragma unroll
        for (int mf = 0; mf < 4; ++mf)
            #pragma unroll
            for (int nf = 0; nf < 4; ++nf)
                acc[mf][nf] = __builtin_amdgcn_mfma_f32_16x16x32_bf16(
                    af[mf], bfr[nf], acc[mf][nf], 0, 0, 0);
        __syncthreads();
    }
}

// ---------------------------------------------------------------------------
// prep: merged. Blocks [0,4096): H rows -> hw1, Hq=bf16(H*w3) into out u16
// cols [3072:3584). Blocks [4096,4352): U rows -> uw2, Ub row-major, Utp
// fragment-major. Wave per row (4 waves / 256-thread block).
// ---------------------------------------------------------------------------
__global__ __launch_bounds__(256) void prep_kernel(
    const float* __restrict__ H, const float* __restrict__ U,
    const float* __restrict__ Ws,
    float* __restrict__ hw1, float* __restrict__ uw2,
    u16* outU, u16* __restrict__ Ub, u16* __restrict__ Utp)
{
    const int w = threadIdx.x >> 6, lane = threadIdx.x & 63;
    if (blockIdx.x < 4096) {
        const int i = blockIdx.x * 4 + w;
        const float* hp = H + (size_t)i * D_DIM + lane * 8;
        const float4 a = *(const float4*)hp;
        const float4 b = *(const float4*)(hp + 4);
        const float4 w1a = *(const float4*)(Ws + lane * 8);
        const float4 w1b = *(const float4*)(Ws + lane * 8 + 4);
        const float4 w3a = *(const float4*)(Ws + 2 * D_DIM + lane * 8);
        const float4 w3b = *(const float4*)(Ws + 2 * D_DIM + lane * 8 + 4);
        float p = a.x*w1a.x + a.y*w1a.y + a.z*w1a.z + a.w*w1a.w
                + b.x*w1b.x + b.y*w1b.y + b.z*w1b.z + b.w*w1b.w;
        #pragma unroll
        for (int m = 1; m < 64; m <<= 1) p += __shfl_xor(p, m);
        if (lane == 0) hw1[i] = p;
        bf16x8 q;
        q[0] = (short)f2bf(a.x * w3a.x); q[1] = (short)f2bf(a.y * w3a.y);
        q[2] = (short)f2bf(a.z * w3a.z); q[3] = (short)f2bf(a.w * w3a.w);
        q[4] = (short)f2bf(b.x * w3b.x); q[5] = (short)f2bf(b.y * w3b.y);
        q[6] = (short)f2bf(b.z * w3b.z); q[7] = (short)f2bf(b.w * w3b.w);
        *(bf16x8*)(outU + (size_t)i * 4096 + 3072 + lane * 8) = q;
    } else {
        const int j = (blockIdx.x - 4096) * 4 + w;
        const float* up = U + (size_t)j * D_DIM + lane * 8;
        const float4 a = *(const float4*)up;
        const float4 b = *(const float4*)(up + 4);
        const float4 w2a = *(const float4*)(Ws + D_DIM + lane * 8);
        const float4 w2b = *(const float4*)(Ws + D_DIM + lane * 8 + 4);
        float p = a.x*w2a.x + a.y*w2a.y + a.z*w2a.z + a.w*w2a.w
                + b.x*w2b.x + b.y*w2b.y + b.z*w2b.z + b.w*w2b.w;
        #pragma unroll
        for (int m = 1; m < 64; m <<= 1) p += __shfl_xor(p, m);
        if (lane == 0) uw2[j] = p;
        bf16x8 q;
        q[0] = (short)f2bf(a.x); q[1] = (short)f2bf(a.y);
        q[2] = (short)f2bf(a.z); q[3] = (short)f2bf(a.w);
        q[4] = (short)f2bf(b.x); q[5] = (short)f2bf(b.y);
        q[6] = (short)f2bf(b.z); q[7] = (short)f2bf(b.w);
        *(bf16x8*)(Ub + (size_t)j * D_DIM + lane * 8) = q;
        const size_t jpart = (size_t)(j >> 5) * 512
                           + (size_t)(((j >> 3) & 3) * 128) + (j & 7);
        #pragma unroll
        for (int s = 0; s < 8; ++s) {
            const int d = lane * 8 + s;
            Utp[(size_t)(d >> 4) * 16384 + jpart + (size_t)(d & 15) * 8] = (u16)q[s];
        }
    }
}

// ---------------------------------------------------------------------------
// s_gemm: S = Hq @ Ub^T + uw2 -> bf16 into out u16 cols [1024:2048) via LDS
// transpose (coalesced 128B/thread stores); pmax[row*8+nb] = local row max.
// ---------------------------------------------------------------------------
__global__ __launch_bounds__(256) void s_gemm(
    u16* outU, const u16* __restrict__ Ub, const float* __restrict__ uw2,
    float* __restrict__ pmax)
{
    __shared__ u16 lds[16896];      // staging [0:16384); Tl [128][132] after
    __shared__ float redf[256];
    const int bid = blockIdx.x;                       // 1024
    const int swz = (bid & 7) * 128 + (bid >> 3);     // XCD swizzle (bijective)
    const int bm = swz >> 3, nb = swz & 7;            // nb fast: A-panel reuse

    f32x4 acc[4][4];
    #pragma unroll
    for (int i = 0; i < 4; ++i)
        #pragma unroll
        for (int j = 0; j < 4; ++j) acc[i][j] = (f32x4){0.f, 0.f, 0.f, 0.f};

    gemm_core<16>(outU + (size_t)bm * 128 * 4096 + 3072, 4096,
                  Ub + (size_t)nb * 128 * 512, 512, lds, acc);

    const int tid = threadIdx.x, lane = tid & 63, w = tid >> 6;
    const int wr = w >> 1, wc = w & 1, fr = lane & 15, quad = lane >> 4;
    float u2[4];
    #pragma unroll
    for (int nf = 0; nf < 4; ++nf) u2[nf] = uw2[nb * 128 + wc * 64 + nf * 16 + fr];

    // add uw2; per-row max -> redf; bf16 into padded transpose tile Tl
    u16* Tl = lds;                                    // [128][132]
    #pragma unroll
    for (int mf = 0; mf < 4; ++mf)
        #pragma unroll
        for (int m = 0; m < 4; ++m) {
            const int row = wr * 64 + mf * 16 + quad * 4 + m;
            float mv = -1e30f;
            #pragma unroll
            for (int nf = 0; nf < 4; ++nf) {
                acc[mf][nf][m] += u2[nf];
                mv = fmaxf(mv, acc[mf][nf][m]);
            }
            mv = fmaxf(mv, __shfl_xor(mv, 1));
            mv = fmaxf(mv, __shfl_xor(mv, 2));
            mv = fmaxf(mv, __shfl_xor(mv, 4));
            mv = fmaxf(mv, __shfl_xor(mv, 8));
            if (fr == 0) redf[wc * 128 + row] = mv;
            #pragma unroll
            for (int nf = 0; nf < 4; ++nf)
                Tl[row * 132 + wc * 64 + nf * 16 + fr] = f2bf(acc[mf][nf][m]);
        }
    __syncthreads();

    if (wc == 0 && fr == 0) {
        #pragma unroll
        for (int mf = 0; mf < 4; ++mf)
            #pragma unroll
            for (int m = 0; m < 4; ++m) {
                const int rr = wr * 64 + mf * 16 + quad * 4 + m;
                pmax[((size_t)bm * 128 + rr) * 8 + nb] =
                    fmaxf(redf[rr], redf[128 + rr]);
            }
    }

    // coalesced copy: 2 threads per row -> 128B contiguous each (u16 units!)
    {
        const int rr = tid >> 1, hf = tid & 1;
        const u16* src = Tl + rr * 132 + hf * 64;
        u16* dst = outU + (size_t)(bm * 128 + rr) * 4096 + 1024 + nb * 128 + hf * 64;
        #pragma unroll
        for (int i = 0; i < 8; ++i)
            *(bf16x8*)(dst + i * 8) = *(const bf16x8*)(src + i * 8);
    }
}

// ---------------------------------------------------------------------------
// bh_kernel: replaces bsoft2 + htilde_partial WITHOUT grid.sync (R9 lesson:
// cooperative grid.sync cost ~80 µs on 8-XCD MI355X). Each of 256 blocks
// REDUNDANTLY computes the global softmax stats M, L over all 16384 rows
// (pmax+hw1 are L2-resident: 512 KB/block, ~4 µs aggregate), then computes
// its own 64-row partial of h_tilde with 1/L folded in.
// ---------------------------------------------------------------------------
__global__ __launch_bounds__(512) void bh_kernel(
    const float* __restrict__ pmax, const float* __restrict__ hw1,
    const float* __restrict__ H, float* __restrict__ part)
{
    const int b = blockIdx.x;     // 256
    const int t = threadIdx.x;    // 512
    __shared__ float red8[8];
    __shared__ float esh[64];
    __shared__ float Msh, Lsh;

    // Pass 1: rs for rows t+512k, running data kept in regs
    float rs[32];
    float m = -1e30f;
    #pragma unroll
    for (int k = 0; k < 32; ++k) {
        const int r = t + k * 512;
        const float4 p0 = *(const float4*)(pmax + (size_t)r * 8);
        const float4 p1 = *(const float4*)(pmax + (size_t)r * 8 + 4);
        rs[k] = fmaxf(fmaxf(fmaxf(p0.x, p0.y), fmaxf(p0.z, p0.w)),
                      fmaxf(fmaxf(p1.x, p1.y), fmaxf(p1.z, p1.w))) + hw1[r];
        m = fmaxf(m, rs[k]);
    }
    #pragma unroll
    for (int s = 1; s < 64; s <<= 1) m = fmaxf(m, __shfl_xor(m, s));
    if ((t & 63) == 0) red8[t >> 6] = m;
    __syncthreads();
    if (t == 0) {
        float M = red8[0];
        #pragma unroll
        for (int i = 1; i < 8; ++i) M = fmaxf(M, red8[i]);
        Msh = M;
    }
    __syncthreads();
    const float M = Msh;
    float l = 0.f;
    #pragma unroll
    for (int k = 0; k < 32; ++k) l += __expf(rs[k] - M);
    #pragma unroll
    for (int s = 1; s < 64; s <<= 1) l += __shfl_xor(l, s);
    if ((t & 63) == 0) red8[t >> 6] = l;
    __syncthreads();
    if (t == 0) {
        float L = 0.f;
        #pragma unroll
        for (int i = 0; i < 8; ++i) L += red8[i];
        Lsh = L;
    }
    __syncthreads();
    const float invL = 1.f / Lsh;

    // own 64 rows' weights (recompute rs for rows b*64+t, t<64)
    if (t < 64) {
        const int r = b * 64 + t;
        const float4 p0 = *(const float4*)(pmax + (size_t)r * 8);
        const float4 p1 = *(const float4*)(pmax + (size_t)r * 8 + 4);
        const float rsv = fmaxf(fmaxf(fmaxf(p0.x, p0.y), fmaxf(p0.z, p0.w)),
                                fmaxf(fmaxf(p1.x, p1.y), fmaxf(p1.z, p1.w))) + hw1[r];
        esh[t] = __expf(rsv - M) * invL;
    }
    __syncthreads();

    // partial h_tilde over own 64 rows, d = t
    float s = 0.f;
    const float* hp = H + (size_t)b * 64 * D_DIM + t;
    #pragma unroll 8
    for (int ri = 0; ri < 64; ++ri)
        s += esh[ri] * hp[(size_t)ri * D_DIM];
    part[(size_t)b * D_DIM + t] = s;
}

__global__ __launch_bounds__(512) void htilde_reduce(
    const float* __restrict__ part, float* __restrict__ ht)
{
    const int d = threadIdx.x;
    float s = 0.f;
    for (int p = 0; p < 256; ++p) s += part[(size_t)p * D_DIM + d];
    ht[d] = s;
}

// ---------------------------------------------------------------------------
// pv_fused: block = 32 rows x all 512 d, 512 threads, 2 blocks/CU. (R8, kept)
// ---------------------------------------------------------------------------
__global__ __launch_bounds__(512, 4) void pv_fused(
    u16* outU, const u16* __restrict__ Utp, const float* __restrict__ H,
    const float* __restrict__ htld)
{
    __shared__ float SPf[32 * 520];          // 66560 B; aliased as u16 P buffer
    u16* SP = (u16*)SPf;                     // [32][1024] u16 (64 KB region)
    const int tid = threadIdx.x, lane = tid & 63, w = tid >> 6;
    const int fr = lane & 15, quad = lane >> 4;
    const int ib = blockIdx.x * 32;

    // Phase 1: stage S rows [ib, ib+32): 8 passes x 512 lanes x 16B
    #pragma unroll
    for (int p = 0; p < 8; ++p) {
        const int slot = p * 512 + tid;      // 0..4095
        const int r  = slot >> 7;            // 0..31
        const int c8 = slot & 127;
        gload16(outU + (size_t)(ib + r) * 4096 + 1024 + (size_t)((c8 ^ (r & 7)) * 8),
                SP + (size_t)slot * 8);
    }
    __syncthreads();

    // Phase 2: in-place softmax; wave w owns rows [4w, 4w+4)
    #pragma unroll
    for (int rr = 0; rr < 4; ++rr) {
        const int r = w * 4 + rr;
        u16* row = SP + (size_t)r * 1024;
        const int s0 = (lane ^ (r & 7)) * 8;
        const int s1 = ((lane + 64) ^ (r & 7)) * 8;
        bf16x8 x0 = *(bf16x8*)(row + s0);
        bf16x8 x1 = *(bf16x8*)(row + s1);
        float f0[8], f1[8];
        float mx = -1e30f;
        #pragma unroll
        for (int i = 0; i < 8; ++i) {
            f0[i] = bf2f((u16)x0[i]); f1[i] = bf2f((u16)x1[i]);
            mx = fmaxf(mx, fmaxf(f0[i], f1[i]));
        }
        #pragma unroll
        for (int s = 1; s < 64; s <<= 1) mx = fmaxf(mx, __shfl_xor(mx, s));
        float sum = 0.f;
        #pragma unroll
        for (int i = 0; i < 8; ++i) {
            f0[i] = __expf(f0[i] - mx); f1[i] = __expf(f1[i] - mx);
            sum += f0[i] + f1[i];
        }
        #pragma unroll
        for (int s = 1; s < 64; s <<= 1) sum += __shfl_xor(sum, s);
        const float inv = 1.f / sum;
        bf16x8 y0, y1;
        #pragma unroll
        for (int i = 0; i < 8; ++i) {
            y0[i] = (short)f2bf(f0[i] * inv);
            y1[i] = (short)f2bf(f1[i] * inv);
        }
        *(bf16x8*)(row + s0) = y0;
        *(bf16x8*)(row + s1) = y1;
    }
    __syncthreads();

    // Phase 3: AQ = P @ Utp; wave w owns d in [64w, 64w+64)
    f32x4 acc[2][4];
    #pragma unroll
    for (int i = 0; i < 2; ++i)
        #pragma unroll
        for (int j = 0; j < 4; ++j) acc[i][j] = (f32x4){0.f, 0.f, 0.f, 0.f};

    const u16* bp = Utp + (size_t)lane * 8;
    bf16x8 bA[4], bB[4];
    #pragma unroll
    for (int nf = 0; nf < 4; ++nf)
        bA[nf] = *(const bf16x8*)(bp + ((size_t)(w * 4 + nf) * 32) * 512);

    for (int ks = 0; ks < 32; ks += 2) {
        #pragma unroll
        for (int nf = 0; nf < 4; ++nf)
            bB[nf] = *(const bf16x8*)(bp + ((size_t)(w * 4 + nf) * 32 + ks + 1) * 512);
        bf16x8 a0[2];
        #pragma unroll
        for (int mf = 0; mf < 2; ++mf)
            a0[mf] = *(const bf16x8*)(SP + (size_t)(mf * 16 + fr) * 1024
                                         + (size_t)(((ks * 4 + quad) ^ (fr & 7)) * 8));
        __builtin_amdgcn_s_setprio(1);
        #pragma unroll
        for (int mf = 0; mf < 2; ++mf)
            #pragma unroll
            for (int nf = 0; nf < 4; ++nf)
                acc[mf][nf] = __builtin_amdgcn_mfma_f32_16x16x32_bf16(
                    a0[mf], bA[nf], acc[mf][nf], 0, 0, 0);
        __builtin_amdgcn_s_setprio(0);
        if (ks + 2 < 32) {
            #pragma unroll
            for (int nf = 0; nf < 4; ++nf)
                bA[nf] = *(const bf16x8*)(bp + ((size_t)(w * 4 + nf) * 32 + ks + 2) * 512);
        }
        bf16x8 a1[2];
        #pragma unroll
        for (int mf = 0; mf < 2; ++mf)
            a1[mf] = *(const bf16x8*)(SP + (size_t)(mf * 16 + fr) * 1024
                                         + (size_t)((((ks + 1) * 4 + quad) ^ (fr & 7)) * 8));
        __builtin_amdgcn_s_setprio(1);
        #pragma unroll
        for (int mf = 0; mf < 2; ++mf)
            #pragma unroll
            for (int nf = 0; nf < 4; ++nf)
                acc[mf][nf] = __builtin_amdgcn_mfma_f32_16x16x32_bf16(
                    a1[mf], bB[nf], acc[mf][nf], 0, 0, 0);
        __builtin_amdgcn_s_setprio(0);
    }
    __syncthreads();   // all P reads done; reuse LDS as f32 AQ buffer

    // Phase 4a: acc -> SPf [row][d] stride 520
    #pragma unroll
    for (int mf = 0; mf < 2; ++mf)
        #pragma unroll
        for (int m = 0; m < 4; ++m) {
            const int r = mf * 16 + quad * 4 + m;
            #pragma unroll
            for (int nf = 0; nf < 4; ++nf)
                SPf[r * 520 + w * 64 + nf * 16 + fr] = acc[mf][nf][m];
        }
    __syncthreads();

    // Phase 4b: coalesced G stores; thread t -> row tid>>4, 8 x float4
    {
        const int r = tid >> 4;              // 0..31
        const int l16 = tid & 15;
        const size_t grow = (size_t)ib + r;
        const float* hrow = H + grow * D_DIM;
        float* ob = (float*)outU + grow * 2048;
        #pragma unroll
        for (int i = 0; i < 8; ++i) {
            const int c = l16 * 4 + i * 64;
            const float4 h  = *(const float4*)(hrow + c);
            const float4 aq = *(const float4*)(&SPf[r * 520 + c]);
            const float4 hv = *(const float4*)(htld + c);
            float4 ha, hh;
            ha.x = h.x * aq.x; ha.y = h.y * aq.y; ha.z = h.z * aq.z; ha.w = h.w * aq.w;
            hh.x = h.x * hv.x; hh.y = h.y * hv.y; hh.z = h.z * hv.z; hh.w = h.w * hv.w;
            *(float4*)(ob + c)        = h;
            *(float4*)(ob + 512 + c)  = aq;
            *(float4*)(ob + 1024 + c) = ha;
            *(float4*)(ob + 1536 + c) = hh;
        }
    }
}

// ---------------------------------------------------------------------------
extern "C" void kernel_launch(void* const* d_in, const int* in_sizes, int n_in,
                              void* d_out, int out_size, void* d_ws, size_t ws_size,
                              hipStream_t stream)
{
    const float* H  = (const float*)d_in[0];
    const float* U  = (const float*)d_in[1];
    const float* Ws = (const float*)d_in[2];
    u16* outU = (u16*)d_out;

    float* uw2   = (float*)d_ws;                   // 1024
    float* hw1   = uw2 + 1024;                     // 16384
    float* htld  = hw1 + T_ROWS;                   // 512
    float* part  = htld + D_DIM;                   // 256*512
    float* pmax  = part + 256 * D_DIM;             // 16384*8
    u16*   Ub    = (u16*)(pmax + (size_t)T_ROWS * 8);   // 1 MB
    u16*   Utp   = Ub + (size_t)J_DIM * D_DIM;          // 1 MB

    hipLaunchKernelGGL(prep_kernel, dim3(4096 + 256), dim3(256), 0, stream,
                       H, U, Ws, hw1, uw2, outU, Ub, Utp);
    hipLaunchKernelGGL(s_gemm, dim3(1024), dim3(256), 0, stream,
                       outU, Ub, uw2, pmax);
    hipLaunchKernelGGL(bh_kernel, dim3(256), dim3(512), 0, stream,
                       pmax, hw1, H, part);
    hipLaunchKernelGGL(htilde_reduce, dim3(1), dim3(512), 0, stream, part, htld);
    hipLaunchKernelGGL(pv_fused, dim3(T_ROWS / 32), dim3(512), 0, stream,
                       outU, Utp, H, htld);
}